// Round 3
// baseline (1643.711 us; speedup 1.0000x reference)
//
#include <hip/hip_runtime.h>
#include <stdint.h>

#define N_ENTC   100000
#define N_ROWC   30000
#define K_INSTC  8
#define N_EDGEC  200000
#define N_RELSC  200          // rel_full has 201 rows (loop_rel appended)
#define NTOTC    (N_ENTC + N_ROWC)   // 130000

// ---------------------------------------------------------------------------
// K1: per-relation-type table  s_edge_tab[t][j] = e_mean_t . W_sheaf[128:,j] + b_sheaf[j]
//     and r_out = rel_embed @ w_rel  (written straight to d_out tail, fp32)
// ---------------------------------------------------------------------------
__global__ __launch_bounds__(256) void k_rel(
    const float* __restrict__ rel_embed, const float* __restrict__ loop_rel,
    const float* __restrict__ W_edge,    const float* __restrict__ b_edge,
    const float* __restrict__ W_sheaf,   const float* __restrict__ b_sheaf,
    const float* __restrict__ w_rel,
    float* __restrict__ s_edge_tab, float* __restrict__ out_rel)
{
  __shared__ float rel[256];
  __shared__ float eproj[256];
  __shared__ float em[128];
  int t = blockIdx.x;        // 0..200
  int c = threadIdx.x;       // 0..255
  rel[c] = (t < N_RELSC) ? rel_embed[t * 256 + c] : loop_rel[c];
  __syncthreads();
  float acc = b_edge[c];
  for (int k = 0; k < 256; ++k) acc += rel[k] * W_edge[k * 256 + c];
  eproj[c] = acc;
  __syncthreads();
  if (c < 128) em[c] = 0.5f * (eproj[c] + eproj[c + 128]);
  __syncthreads();
  if (c < 2) {
    float s = b_sheaf[c];
    for (int hh = 0; hh < 128; ++hh) s += em[hh] * W_sheaf[(128 + hh) * 2 + c];
    s_edge_tab[t * 2 + c] = s;
  }
  if (t < N_RELSC) {
    float ro = 0.f;
    for (int k = 0; k < 256; ++k) ro += rel[k] * w_rel[k * 256 + c];
    out_rel[t * 256 + c] = ro;
  }
}

// ---------------------------------------------------------------------------
// K2: instance-dict embedding: masked mean of up to 8 gathered x rows
// ---------------------------------------------------------------------------
__global__ __launch_bounds__(256) void k_inst(
    const float* __restrict__ x, const int* __restrict__ ids,
    float* __restrict__ inst)
{
  int r = blockIdx.x;         // 0..N_ROWC-1
  int c = threadIdx.x;        // 0..255
  float s = 0.f; int cnt = 0;
#pragma unroll
  for (int k = 0; k < K_INSTC; ++k) {
    int id = ids[r * K_INSTC + k];
    if (id >= 0) { s += x[(size_t)id * 256 + c]; cnt++; }
  }
  inst[(size_t)r * 256 + c] = s / (float)cnt;   // cnt >= 1 guaranteed
}

// ---------------------------------------------------------------------------
// K3: fused projection. Per 48-row tile:
//   y = x_all @ W_in + b_in         (fp32, 6x8 microtile, LDS-tiled)
//   h[v*2+j] = y[:,j*128:] @ W_conv + b_conv
//   s_node[v][j] = mean-head(y) . W_sheaf[:128, j]
// LDS: union{ p1: 32x256 W + 48x33 xb = 39.1 KB ; p2: 48x256 y + 16x128 wc = 56 KB }
// ---------------------------------------------------------------------------
#define TM  48
#define KT  32
#define KT2 16

__global__ __launch_bounds__(256, 2) void k_proj(
    const float* __restrict__ x, const float* __restrict__ inst,
    const float* __restrict__ W_in,  const float* __restrict__ b_in,
    const float* __restrict__ W_conv, const float* __restrict__ b_conv,
    const float* __restrict__ W_sheaf,
    float* __restrict__ h, float* __restrict__ s_node)
{
  __shared__ union {
    struct { float W[KT * 256]; float xb[TM * 33]; } p1;   // 39.1 KB
    struct { float y[TM * 256]; float wc[KT2 * 128]; } p2; // 56 KB
  } sm;

  int tid = threadIdx.x;
  int row0 = blockIdx.x * TM;
  int tc = tid & 31, tr = tid >> 5;       // 32 col-groups x 8 row-groups

  float acc[6][8];
#pragma unroll
  for (int a = 0; a < 6; ++a)
#pragma unroll
    for (int b = 0; b < 8; ++b) acc[a][b] = 0.f;

  // ---- phase 1: y = x_all @ W_in ----
  for (int kt = 0; kt < 256; kt += KT) {
    // load W_in tile (32 x 256) fp32 -> LDS : 2048 float4, 8 per thread
#pragma unroll
    for (int i = 0; i < 8; ++i) {
      int off = (tid + i * 256) * 4;
      int k = off >> 8, c = off & 255;
      float4 w4 = *(const float4*)(W_in + (size_t)(kt + k) * 256 + c);
      *(float4*)&sm.p1.W[k * 256 + c] = w4;
    }
    // load x tile (48 rows x 32 k) : 384 float4
#pragma unroll
    for (int i = 0; i < 2; ++i) {
      int idx4 = tid + i * 256;
      if (idx4 < (TM * KT) / 4) {
        int off = idx4 * 4;
        int r = off >> 5, kk = off & 31;
        int row = row0 + r;
        float4 v = make_float4(0.f, 0.f, 0.f, 0.f);
        if (row < N_ENTC) {
          v = *(const float4*)(x + (size_t)row * 256 + kt + kk);
        } else if (row < NTOTC) {
          v = *(const float4*)(inst + (size_t)(row - N_ENTC) * 256 + kt + kk);
        }
        float* xp = &sm.p1.xb[r * 33 + kk];
        xp[0] = v.x; xp[1] = v.y; xp[2] = v.z; xp[3] = v.w;
      }
    }
    __syncthreads();
#pragma unroll
    for (int k = 0; k < KT; ++k) {
      float4 w0 = *(const float4*)&sm.p1.W[k * 256 + tc * 8];
      float4 w1 = *(const float4*)&sm.p1.W[k * 256 + tc * 8 + 4];
#pragma unroll
      for (int rr = 0; rr < 6; ++rr) {
        float xv = sm.p1.xb[(tr * 6 + rr) * 33 + k];
        acc[rr][0] += xv * w0.x; acc[rr][1] += xv * w0.y;
        acc[rr][2] += xv * w0.z; acc[rr][3] += xv * w0.w;
        acc[rr][4] += xv * w1.x; acc[rr][5] += xv * w1.y;
        acc[rr][6] += xv * w1.z; acc[rr][7] += xv * w1.w;
      }
    }
    __syncthreads();
  }

  // ---- write y (+b_in) to LDS (aliases phase-1 region; barrier above protects) ----
  float bi[8];
#pragma unroll
  for (int cc = 0; cc < 8; ++cc) bi[cc] = b_in[tc * 8 + cc];
#pragma unroll
  for (int rr = 0; rr < 6; ++rr) {
    float4 v0, v1;
    v0.x = acc[rr][0] + bi[0]; v0.y = acc[rr][1] + bi[1];
    v0.z = acc[rr][2] + bi[2]; v0.w = acc[rr][3] + bi[3];
    v1.x = acc[rr][4] + bi[4]; v1.y = acc[rr][5] + bi[5];
    v1.z = acc[rr][6] + bi[6]; v1.w = acc[rr][7] + bi[7];
    *(float4*)&sm.p2.y[(tr * 6 + rr) * 256 + tc * 8] = v0;
    *(float4*)&sm.p2.y[(tr * 6 + rr) * 256 + tc * 8 + 4] = v1;
  }
  __syncthreads();

  // ---- phase 3: s_node (threads 0..95; reads y only) ----
  if (tid < TM * 2) {
    int r = tid >> 1, j = tid & 1;
    int row = row0 + r;
    if (row < NTOTC) {
      float s = 0.f;
      const float* yr = &sm.p2.y[r * 256];
      for (int hh = 0; hh < 128; ++hh) {
        float xm = 0.5f * (yr[hh] + yr[hh + 128]);
        s += xm * W_sheaf[hh * 2 + j];
      }
      s_node[(size_t)row * 2 + j] = s;
    }
  }

  // ---- phase 2: h = y @ W_conv + b_conv (M=96 virtual rows (v,j), N=128, K=128) ----
  int tc2 = tid & 15, tr2 = tid >> 4;      // 16 col-groups x 16 row-groups
  float acc2[6][8];
#pragma unroll
  for (int a = 0; a < 6; ++a)
#pragma unroll
    for (int b = 0; b < 8; ++b) acc2[a][b] = 0.f;
  int yoff[6];
#pragma unroll
  for (int rr = 0; rr < 6; ++rr) {
    int u = tr2 * 6 + rr;                  // virtual row in [0,96)
    yoff[rr] = (u >> 1) * 256 + (u & 1) * 128;
  }
  for (int kt = 0; kt < 128; kt += KT2) {
    // load W_conv tile (16 x 128) : 512 float4, 2 per thread
#pragma unroll
    for (int i = 0; i < 2; ++i) {
      int off = (tid + i * 256) * 4;
      int k = off >> 7, c = off & 127;
      float4 w4 = *(const float4*)(W_conv + (size_t)(kt + k) * 128 + c);
      *(float4*)&sm.p2.wc[k * 128 + c] = w4;
    }
    __syncthreads();
#pragma unroll
    for (int k = 0; k < KT2; ++k) {
      float4 w0 = *(const float4*)&sm.p2.wc[k * 128 + tc2 * 8];
      float4 w1 = *(const float4*)&sm.p2.wc[k * 128 + tc2 * 8 + 4];
#pragma unroll
      for (int rr = 0; rr < 6; ++rr) {
        float xv = sm.p2.y[yoff[rr] + kt + k];
        acc2[rr][0] += xv * w0.x; acc2[rr][1] += xv * w0.y;
        acc2[rr][2] += xv * w0.z; acc2[rr][3] += xv * w0.w;
        acc2[rr][4] += xv * w1.x; acc2[rr][5] += xv * w1.y;
        acc2[rr][6] += xv * w1.z; acc2[rr][7] += xv * w1.w;
      }
    }
    __syncthreads();
  }
  float bc[8];
#pragma unroll
  for (int cc = 0; cc < 8; ++cc) bc[cc] = b_conv[tc2 * 8 + cc];
#pragma unroll
  for (int rr = 0; rr < 6; ++rr) {
    int u = tr2 * 6 + rr;
    if (row0 + (u >> 1) < NTOTC) {
      size_t hrow = (size_t)(row0 * 2 + u);
      float4 v0, v1;
      v0.x = acc2[rr][0] + bc[0]; v0.y = acc2[rr][1] + bc[1];
      v0.z = acc2[rr][2] + bc[2]; v0.w = acc2[rr][3] + bc[3];
      v1.x = acc2[rr][4] + bc[4]; v1.y = acc2[rr][5] + bc[5];
      v1.z = acc2[rr][6] + bc[6]; v1.w = acc2[rr][7] + bc[7];
      *(float4*)&h[hrow * 128 + tc2 * 8] = v0;
      *(float4*)&h[hrow * 128 + tc2 * 8 + 4] = v1;
    }
  }
}

// ---------------------------------------------------------------------------
// K4a: per-edge alphas (tanh) + Dn scatter (entity slots only)
// ---------------------------------------------------------------------------
__global__ __launch_bounds__(256) void k_alpha(
    const int* __restrict__ ei0, const int* __restrict__ ei1,
    const int* __restrict__ etype,
    const float* __restrict__ s_node, const float* __restrict__ s_edge_tab,
    float* __restrict__ alph, float* __restrict__ Dn)
{
  int e = blockIdx.x * 256 + threadIdx.x;
  if (e >= N_EDGEC) return;
  int t = ei0[e], rI = ei1[e], ty = etype[e];
  float se0 = s_edge_tab[ty * 2 + 0], se1 = s_edge_tab[ty * 2 + 1];
  const float* snI = &s_node[(size_t)(N_ENTC + rI) * 2];
  const float* snT = &s_node[(size_t)t * 2];
  float a10 = tanhf(snI[0] + se0);
  float a11 = tanhf(snI[1] + se1);
  float a20 = tanhf(snT[0] + se0);
  float a21 = tanhf(snT[1] + se1);
  float4 av; av.x = a10; av.y = a11; av.z = a20; av.w = a21;
  *(float4*)&alph[(size_t)e * 4] = av;
  atomicAdd(&Dn[t * 2 + 0], a20 * a20);
  atomicAdd(&Dn[t * 2 + 1], a21 * a21);
}

// ---------------------------------------------------------------------------
// K4: per-edge diffusion scatter into entity accumulator (Binv == 0.5 always)
//     out_acc[t,j,:] += a2 * 0.5*(a1*h[inst,j,:] + a2*h[t,j,:])
// ---------------------------------------------------------------------------
__global__ __launch_bounds__(256) void k_scatter(
    const int* __restrict__ ei0, const int* __restrict__ ei1,
    const float* __restrict__ alph, const float* __restrict__ h,
    float* __restrict__ out_acc)
{
  int j  = threadIdx.x >> 7;      // head
  int hh = threadIdx.x & 127;     // channel
  int e0 = blockIdx.x * 4;
#pragma unroll
  for (int i = 0; i < 4; ++i) {
    int e = e0 + i;
    if (e >= N_EDGEC) break;
    int t = ei0[e], rI = ei1[e];
    float a1 = alph[(size_t)e * 4 + j];
    float a2 = alph[(size_t)e * 4 + 2 + j];
    float hr = h[((size_t)(N_ENTC + rI) * 2 + j) * 128 + hh];
    float ht = h[((size_t)t * 2 + j) * 128 + hh];
    float val = 0.5f * a2 * (a1 * hr + a2 * ht);
    atomicAdd(&out_acc[((size_t)t * 2 + j) * 128 + hh], val);
  }
}

// ---------------------------------------------------------------------------
// K5: finalize rows (Dinv, +conv_bias, +residual h, ELU, +mod_bias),
//     in-place prebn store, fp64 BN-stat accumulation
// ---------------------------------------------------------------------------
__global__ __launch_bounds__(256) void k_final(
    const float* __restrict__ h, const float* __restrict__ Dn,
    const float* __restrict__ conv_bias, const float* __restrict__ mod_bias,
    float* __restrict__ out_acc, double* __restrict__ bnacc)
{
  int tid = threadIdx.x;
  int j = tid >> 7, hh = tid & 127;
  float cb = conv_bias[hh];
  float mb = mod_bias[tid];
  double s = 0.0, sq = 0.0;
  int v0 = blockIdx.x * 128;
  for (int rr = 0; rr < 128; ++rr) {
    int v = v0 + rr;
    if (v >= N_ENTC) break;
    size_t idx = (size_t)v * 256 + tid;
    float dn = Dn[v * 2 + j];
    float dinv = (dn > 0.f) ? (1.0f / dn) : 0.f;
    float o = out_acc[idx] * dinv + cb + h[idx];
    o = (o > 0.f) ? o : expm1f(o);     // ELU
    o += mb;
    out_acc[idx] = o;                  // in-place prebn
    s += (double)o; sq += (double)o * (double)o;
  }
  atomicAdd(&bnacc[tid], s);
  atomicAdd(&bnacc[256 + tid], sq);
}

// ---------------------------------------------------------------------------
// K6: BN affine coefficients (biased var, eps=1e-5)
// ---------------------------------------------------------------------------
__global__ void k_bnstat(const double* __restrict__ bnacc,
                         const float* __restrict__ gamma, const float* __restrict__ beta,
                         float* __restrict__ ss)
{
  int c = threadIdx.x;
  double mu  = bnacc[c] / (double)N_ENTC;
  double var = bnacc[256 + c] / (double)N_ENTC - mu * mu;
  double istd = 1.0 / sqrt(var + 1e-5);
  float sc = (float)((double)gamma[c] * istd);
  float sh = (float)((double)beta[c] - mu * (double)sc);
  ss[c] = sc; ss[256 + c] = sh;
}

// ---------------------------------------------------------------------------
// K7: normalize + fp32 store of out_ent
// ---------------------------------------------------------------------------
__global__ __launch_bounds__(256) void k_store(
    const float* __restrict__ prebn, const float* __restrict__ ss,
    float* __restrict__ out)
{
  size_t stride = (size_t)gridDim.x * 256 * 4;
  for (size_t i = ((size_t)blockIdx.x * 256 + threadIdx.x) * 4;
       i < (size_t)N_ENTC * 256; i += stride) {
    float4 a = *(const float4*)(prebn + i);
    int c = (int)(i & 255);
    float4 o;
    o.x = a.x * ss[c + 0] + ss[256 + c + 0];
    o.y = a.y * ss[c + 1] + ss[256 + c + 1];
    o.z = a.z * ss[c + 2] + ss[256 + c + 2];
    o.w = a.w * ss[c + 3] + ss[256 + c + 3];
    *(float4*)(out + i) = o;
  }
}

// ---------------------------------------------------------------------------
// Workspace layout (peak 240,568,192 B):
//   h        [0, 133,120,000)                        fp32, alive whole pass
//   Dn       [133,120,000, 133,920,000)              zeroed by memset #1
//   bnacc    [133,920,000, 133,924,096)              zeroed by memset #1
//   s_node   [133,924,096, 134,964,096)
//   alph     [134,964,096, 138,164,096)
//   ss       [138,164,096, 138,166,144)
//   s_edge   [138,166,144, 138,168,192)
//   BIG      [138,168,192, 240,568,192)              inst (first 30.72MB, dead
//            after k_proj) then re-used as out_acc (zeroed by memset #2)
// ---------------------------------------------------------------------------
extern "C" void kernel_launch(void* const* d_in, const int* in_sizes, int n_in,
                              void* d_out, int out_size, void* d_ws, size_t ws_size,
                              hipStream_t stream)
{
  (void)in_sizes; (void)n_in; (void)out_size; (void)ws_size;

  const float* x         = (const float*)d_in[0];
  const int*   edge_idx  = (const int*)d_in[1];
  // d_in[2] = edge_order (unused)
  const int*   etype     = (const int*)d_in[3];
  const float* rel_embed = (const float*)d_in[4];
  const int*   ids       = (const int*)d_in[5];
  const float* W_in      = (const float*)d_in[6];
  const float* b_in      = (const float*)d_in[7];
  const float* W_edge    = (const float*)d_in[8];
  const float* b_edge    = (const float*)d_in[9];
  const float* W_sheaf   = (const float*)d_in[10];
  const float* b_sheaf   = (const float*)d_in[11];
  const float* W_conv    = (const float*)d_in[12];
  const float* b_conv    = (const float*)d_in[13];
  const float* conv_bias = (const float*)d_in[14];
  const float* w_rel     = (const float*)d_in[15];
  const float* loop_rel  = (const float*)d_in[16];
  const float* mod_bias  = (const float*)d_in[17];
  const float* bn_gamma  = (const float*)d_in[18];
  const float* bn_beta   = (const float*)d_in[19];

  const int* ei0 = edge_idx;            // target entities
  const int* ei1 = edge_idx + N_EDGEC;  // source instance rows

  char* ws = (char*)d_ws;
  const size_t OFF_H     = 0;                                   // 133,120,000
  const size_t OFF_DN    = OFF_H     + (size_t)NTOTC*256*4;     //     800,000
  const size_t OFF_BN    = OFF_DN    + (size_t)N_ENTC*2*4;      //       4,096
  const size_t OFF_SNODE = OFF_BN    + 4096;                    //   1,040,000
  const size_t OFF_ALPH  = OFF_SNODE + (size_t)NTOTC*2*4;       //   3,200,000
  const size_t OFF_SS    = OFF_ALPH  + (size_t)N_EDGEC*4*4;     //       2,048
  const size_t OFF_SEDGE = OFF_SS    + 2048;                    //       2,048
  const size_t OFF_BIG   = OFF_SEDGE + 2048;                    // 102,400,000

  float*  h       = (float*)(ws + OFF_H);
  float*  Dn      = (float*)(ws + OFF_DN);
  double* bnacc   = (double*)(ws + OFF_BN);
  float*  s_node  = (float*)(ws + OFF_SNODE);
  float*  alph    = (float*)(ws + OFF_ALPH);
  float*  ss      = (float*)(ws + OFF_SS);
  float*  s_edge  = (float*)(ws + OFF_SEDGE);
  float*  inst    = (float*)(ws + OFF_BIG);   // dead after k_proj
  float*  out_acc = (float*)(ws + OFF_BIG);   // zeroed after k_proj

  float* out_ent = (float*)d_out;
  float* out_rel = (float*)d_out + (size_t)N_ENTC * 256;

  // memset #1: Dn + bnacc (contiguous)
  hipMemsetAsync(ws + OFF_DN, 0, (size_t)N_ENTC*2*4 + 4096, stream);

  k_rel<<<201, 256, 0, stream>>>(rel_embed, loop_rel, W_edge, b_edge,
                                 W_sheaf, b_sheaf, w_rel, s_edge, out_rel);
  k_inst<<<N_ROWC, 256, 0, stream>>>(x, ids, inst);
  k_proj<<<(NTOTC + TM - 1) / TM, 256, 0, stream>>>(x, inst, W_in, b_in,
                                                    W_conv, b_conv, W_sheaf,
                                                    h, s_node);
  // memset #2: out_acc (re-uses the inst region, which is now dead)
  hipMemsetAsync(ws + OFF_BIG, 0, (size_t)N_ENTC*256*4, stream);

  k_alpha<<<(N_EDGEC + 255) / 256, 256, 0, stream>>>(ei0, ei1, etype,
                                                     s_node, s_edge, alph, Dn);
  k_scatter<<<(N_EDGEC + 3) / 4, 256, 0, stream>>>(ei0, ei1, alph, h, out_acc);
  k_final<<<(N_ENTC + 127) / 128, 256, 0, stream>>>(h, Dn, conv_bias, mod_bias,
                                                    out_acc, bnacc);
  k_bnstat<<<1, 256, 0, stream>>>(bnacc, bn_gamma, bn_beta, ss);
  k_store<<<8192, 256, 0, stream>>>(out_acc, ss, out_ent);
}

// Round 4
// 1203.033 us; speedup vs baseline: 1.3663x; 1.3663x over previous
//
#include <hip/hip_runtime.h>
#include <stdint.h>

#define N_ENTC   100000
#define N_ROWC   30000
#define K_INSTC  8
#define N_EDGEC  200000
#define N_RELSC  200          // rel_full has 201 rows (loop_rel appended)
#define NTOTC    (N_ENTC + N_ROWC)   // 130000

// ---------------------------------------------------------------------------
// K1: per-relation-type table  s_edge_tab[t][j] = e_mean_t . W_sheaf[128:,j] + b_sheaf[j]
//     and r_out = rel_embed @ w_rel  (written straight to d_out tail, fp32)
// ---------------------------------------------------------------------------
__global__ __launch_bounds__(256) void k_rel(
    const float* __restrict__ rel_embed, const float* __restrict__ loop_rel,
    const float* __restrict__ W_edge,    const float* __restrict__ b_edge,
    const float* __restrict__ W_sheaf,   const float* __restrict__ b_sheaf,
    const float* __restrict__ w_rel,
    float* __restrict__ s_edge_tab, float* __restrict__ out_rel)
{
  __shared__ float rel[256];
  __shared__ float eproj[256];
  __shared__ float em[128];
  int t = blockIdx.x;        // 0..200
  int c = threadIdx.x;       // 0..255
  rel[c] = (t < N_RELSC) ? rel_embed[t * 256 + c] : loop_rel[c];
  __syncthreads();
  float acc = b_edge[c];
  for (int k = 0; k < 256; ++k) acc += rel[k] * W_edge[k * 256 + c];
  eproj[c] = acc;
  __syncthreads();
  if (c < 128) em[c] = 0.5f * (eproj[c] + eproj[c + 128]);
  __syncthreads();
  if (c < 2) {
    float s = b_sheaf[c];
    for (int hh = 0; hh < 128; ++hh) s += em[hh] * W_sheaf[(128 + hh) * 2 + c];
    s_edge_tab[t * 2 + c] = s;
  }
  if (t < N_RELSC) {
    float ro = 0.f;
    for (int k = 0; k < 256; ++k) ro += rel[k] * w_rel[k * 256 + c];
    out_rel[t * 256 + c] = ro;
  }
}

// ---------------------------------------------------------------------------
// K2: instance-dict embedding: masked mean of up to 8 gathered x rows
// ---------------------------------------------------------------------------
__global__ __launch_bounds__(256) void k_inst(
    const float* __restrict__ x, const int* __restrict__ ids,
    float* __restrict__ inst)
{
  int r = blockIdx.x;         // 0..N_ROWC-1
  int c = threadIdx.x;        // 0..255
  float s = 0.f; int cnt = 0;
#pragma unroll
  for (int k = 0; k < K_INSTC; ++k) {
    int id = ids[r * K_INSTC + k];
    if (id >= 0) { s += x[(size_t)id * 256 + c]; cnt++; }
  }
  inst[(size_t)r * 256 + c] = s / (float)cnt;   // cnt >= 1 guaranteed
}

// ---------------------------------------------------------------------------
// K3: fused projection. Per 48-row tile:
//   y = x_all @ W_in + b_in         (fp32, 6x8 microtile, LDS-tiled)
//   h[v*2+j] = y[:,j*128:] @ W_conv + b_conv
//   s_node[v][j] = mean-head(y) . W_sheaf[:128, j]
// Bank-conflict-free layout:
//   - thread cols = {tc*4..+3} u {128+tc*4..+3}  -> 16B/lane consecutive LDS ops
//   - y padded to stride 260 (mod 32 = 4)        -> phase-2 scalar reads distinct banks
//   - phase-3 skewed hh start (5*r & 127)        -> bank (9r+i)%32, gcd(9,32)=1
// LDS: union{ p1: 32x256 W + 48x33 xb = 39.1 KB ; p2: 48x260 y + 16x128 wc = 58.1 KB }
// ---------------------------------------------------------------------------
#define TM  48
#define KT  32
#define KT2 16
#define YS  260     // padded y row stride

__global__ __launch_bounds__(256, 2) void k_proj(
    const float* __restrict__ x, const float* __restrict__ inst,
    const float* __restrict__ W_in,  const float* __restrict__ b_in,
    const float* __restrict__ W_conv, const float* __restrict__ b_conv,
    const float* __restrict__ W_sheaf,
    float* __restrict__ h, float* __restrict__ s_node)
{
  __shared__ union {
    struct { float W[KT * 256]; float xb[TM * 33]; } p1;   // 39.1 KB
    struct { float y[TM * YS]; float wc[KT2 * 128]; } p2;  // 58.1 KB
  } sm;

  int tid = threadIdx.x;
  int row0 = blockIdx.x * TM;
  int tc = tid & 31, tr = tid >> 5;       // 32 col-groups x 8 row-groups

  float acc[6][8];
#pragma unroll
  for (int a = 0; a < 6; ++a)
#pragma unroll
    for (int b = 0; b < 8; ++b) acc[a][b] = 0.f;

  // ---- phase 1: y = x_all @ W_in ----
  for (int kt = 0; kt < 256; kt += KT) {
    // load W_in tile (32 x 256) fp32 -> LDS : 2048 float4, 8 per thread
#pragma unroll
    for (int i = 0; i < 8; ++i) {
      int off = (tid + i * 256) * 4;
      int k = off >> 8, c = off & 255;
      float4 w4 = *(const float4*)(W_in + (size_t)(kt + k) * 256 + c);
      *(float4*)&sm.p1.W[k * 256 + c] = w4;
    }
    // load x tile (48 rows x 32 k) : 384 float4
#pragma unroll
    for (int i = 0; i < 2; ++i) {
      int idx4 = tid + i * 256;
      if (idx4 < (TM * KT) / 4) {
        int off = idx4 * 4;
        int r = off >> 5, kk = off & 31;
        int row = row0 + r;
        float4 v = make_float4(0.f, 0.f, 0.f, 0.f);
        if (row < N_ENTC) {
          v = *(const float4*)(x + (size_t)row * 256 + kt + kk);
        } else if (row < NTOTC) {
          v = *(const float4*)(inst + (size_t)(row - N_ENTC) * 256 + kt + kk);
        }
        float* xp = &sm.p1.xb[r * 33 + kk];
        xp[0] = v.x; xp[1] = v.y; xp[2] = v.z; xp[3] = v.w;
      }
    }
    __syncthreads();
#pragma unroll
    for (int k = 0; k < KT; ++k) {
      // conflict-free: lane tc reads 16B at 16*tc (and +512B)
      float4 w0 = *(const float4*)&sm.p1.W[k * 256 + tc * 4];
      float4 w1 = *(const float4*)&sm.p1.W[k * 256 + 128 + tc * 4];
#pragma unroll
      for (int rr = 0; rr < 6; ++rr) {
        float xv = sm.p1.xb[(tr * 6 + rr) * 33 + k];
        acc[rr][0] += xv * w0.x; acc[rr][1] += xv * w0.y;
        acc[rr][2] += xv * w0.z; acc[rr][3] += xv * w0.w;
        acc[rr][4] += xv * w1.x; acc[rr][5] += xv * w1.y;
        acc[rr][6] += xv * w1.z; acc[rr][7] += xv * w1.w;
      }
    }
    __syncthreads();
  }

  // ---- write y (+b_in) to LDS (cols tc*4.. and 128+tc*4..) ----
  float bi[8];
#pragma unroll
  for (int cc = 0; cc < 4; ++cc) { bi[cc] = b_in[tc * 4 + cc]; bi[4 + cc] = b_in[128 + tc * 4 + cc]; }
#pragma unroll
  for (int rr = 0; rr < 6; ++rr) {
    float4 v0, v1;
    v0.x = acc[rr][0] + bi[0]; v0.y = acc[rr][1] + bi[1];
    v0.z = acc[rr][2] + bi[2]; v0.w = acc[rr][3] + bi[3];
    v1.x = acc[rr][4] + bi[4]; v1.y = acc[rr][5] + bi[5];
    v1.z = acc[rr][6] + bi[6]; v1.w = acc[rr][7] + bi[7];
    *(float4*)&sm.p2.y[(tr * 6 + rr) * YS + tc * 4] = v0;
    *(float4*)&sm.p2.y[(tr * 6 + rr) * YS + 128 + tc * 4] = v1;
  }
  __syncthreads();

  // ---- phase 3: s_node (threads 0..95; skewed hh to avoid same-bank rows) ----
  if (tid < TM * 2) {
    int r = tid >> 1, j = tid & 1;
    int row = row0 + r;
    if (row < NTOTC) {
      float s = 0.f;
      const float* yr = &sm.p2.y[r * YS];
      int start = (5 * r) & 127;
      for (int i = 0; i < 128; ++i) {
        int hh = (start + i) & 127;
        float xm = 0.5f * (yr[hh] + yr[hh + 128]);
        s += xm * W_sheaf[hh * 2 + j];
      }
      s_node[(size_t)row * 2 + j] = s;
    }
  }

  // ---- phase 2: h = y @ W_conv + b_conv (M=96 virtual rows (v,j), N=128, K=128) ----
  int tc2 = tid & 15, tr2 = tid >> 4;      // 16 col-groups x 16 row-groups
  float acc2[6][8];
#pragma unroll
  for (int a = 0; a < 6; ++a)
#pragma unroll
    for (int b = 0; b < 8; ++b) acc2[a][b] = 0.f;
  int yoff[6];
#pragma unroll
  for (int rr = 0; rr < 6; ++rr) {
    int u = tr2 * 6 + rr;                  // virtual row in [0,96)
    yoff[rr] = (u >> 1) * YS + (u & 1) * 128;
  }
  for (int kt = 0; kt < 128; kt += KT2) {
    // load W_conv tile (16 x 128) : 512 float4, 2 per thread
#pragma unroll
    for (int i = 0; i < 2; ++i) {
      int off = (tid + i * 256) * 4;
      int k = off >> 7, c = off & 127;
      float4 w4 = *(const float4*)(W_conv + (size_t)(kt + k) * 128 + c);
      *(float4*)&sm.p2.wc[k * 128 + c] = w4;
    }
    __syncthreads();
#pragma unroll
    for (int k = 0; k < KT2; ++k) {
      float4 w0 = *(const float4*)&sm.p2.wc[k * 128 + tc2 * 4];
      float4 w1 = *(const float4*)&sm.p2.wc[k * 128 + 64 + tc2 * 4];
#pragma unroll
      for (int rr = 0; rr < 6; ++rr) {
        float xv = sm.p2.y[yoff[rr] + kt + k];
        acc2[rr][0] += xv * w0.x; acc2[rr][1] += xv * w0.y;
        acc2[rr][2] += xv * w0.z; acc2[rr][3] += xv * w0.w;
        acc2[rr][4] += xv * w1.x; acc2[rr][5] += xv * w1.y;
        acc2[rr][6] += xv * w1.z; acc2[rr][7] += xv * w1.w;
      }
    }
    __syncthreads();
  }
  float bc[8];
#pragma unroll
  for (int cc = 0; cc < 4; ++cc) { bc[cc] = b_conv[tc2 * 4 + cc]; bc[4 + cc] = b_conv[64 + tc2 * 4 + cc]; }
#pragma unroll
  for (int rr = 0; rr < 6; ++rr) {
    int u = tr2 * 6 + rr;
    if (row0 + (u >> 1) < NTOTC) {
      size_t hrow = (size_t)(row0 * 2 + u);
      float4 v0, v1;
      v0.x = acc2[rr][0] + bc[0]; v0.y = acc2[rr][1] + bc[1];
      v0.z = acc2[rr][2] + bc[2]; v0.w = acc2[rr][3] + bc[3];
      v1.x = acc2[rr][4] + bc[4]; v1.y = acc2[rr][5] + bc[5];
      v1.z = acc2[rr][6] + bc[6]; v1.w = acc2[rr][7] + bc[7];
      *(float4*)&h[hrow * 128 + tc2 * 4] = v0;
      *(float4*)&h[hrow * 128 + 64 + tc2 * 4] = v1;
    }
  }
}

// ---------------------------------------------------------------------------
// K4a: per-edge alphas (tanh) + Dn scatter (entity slots only)
// ---------------------------------------------------------------------------
__global__ __launch_bounds__(256) void k_alpha(
    const int* __restrict__ ei0, const int* __restrict__ ei1,
    const int* __restrict__ etype,
    const float* __restrict__ s_node, const float* __restrict__ s_edge_tab,
    float* __restrict__ alph, float* __restrict__ Dn)
{
  int e = blockIdx.x * 256 + threadIdx.x;
  if (e >= N_EDGEC) return;
  int t = ei0[e], rI = ei1[e], ty = etype[e];
  float se0 = s_edge_tab[ty * 2 + 0], se1 = s_edge_tab[ty * 2 + 1];
  const float* snI = &s_node[(size_t)(N_ENTC + rI) * 2];
  const float* snT = &s_node[(size_t)t * 2];
  float a10 = tanhf(snI[0] + se0);
  float a11 = tanhf(snI[1] + se1);
  float a20 = tanhf(snT[0] + se0);
  float a21 = tanhf(snT[1] + se1);
  float4 av; av.x = a10; av.y = a11; av.z = a20; av.w = a21;
  *(float4*)&alph[(size_t)e * 4] = av;
  atomicAdd(&Dn[t * 2 + 0], a20 * a20);
  atomicAdd(&Dn[t * 2 + 1], a21 * a21);
}

// ---------------------------------------------------------------------------
// K4: per-edge diffusion scatter into entity accumulator (Binv == 0.5 always)
//     out_acc[t,j,:] += a2 * 0.5*(a1*h[inst,j,:] + a2*h[t,j,:])
// ---------------------------------------------------------------------------
__global__ __launch_bounds__(256) void k_scatter(
    const int* __restrict__ ei0, const int* __restrict__ ei1,
    const float* __restrict__ alph, const float* __restrict__ h,
    float* __restrict__ out_acc)
{
  int j  = threadIdx.x >> 7;      // head
  int hh = threadIdx.x & 127;     // channel
  int e0 = blockIdx.x * 4;
#pragma unroll
  for (int i = 0; i < 4; ++i) {
    int e = e0 + i;
    if (e >= N_EDGEC) break;
    int t = ei0[e], rI = ei1[e];
    float a1 = alph[(size_t)e * 4 + j];
    float a2 = alph[(size_t)e * 4 + 2 + j];
    float hr = h[((size_t)(N_ENTC + rI) * 2 + j) * 128 + hh];
    float ht = h[((size_t)t * 2 + j) * 128 + hh];
    float val = 0.5f * a2 * (a1 * hr + a2 * ht);
    atomicAdd(&out_acc[((size_t)t * 2 + j) * 128 + hh], val);
  }
}

// ---------------------------------------------------------------------------
// K5: finalize rows (Dinv, +conv_bias, +residual h, ELU, +mod_bias),
//     in-place prebn store, fp64 BN-stat accumulation
// ---------------------------------------------------------------------------
__global__ __launch_bounds__(256) void k_final(
    const float* __restrict__ h, const float* __restrict__ Dn,
    const float* __restrict__ conv_bias, const float* __restrict__ mod_bias,
    float* __restrict__ out_acc, double* __restrict__ bnacc)
{
  int tid = threadIdx.x;
  int j = tid >> 7, hh = tid & 127;
  float cb = conv_bias[hh];
  float mb = mod_bias[tid];
  double s = 0.0, sq = 0.0;
  int v0 = blockIdx.x * 128;
  for (int rr = 0; rr < 128; ++rr) {
    int v = v0 + rr;
    if (v >= N_ENTC) break;
    size_t idx = (size_t)v * 256 + tid;
    float dn = Dn[v * 2 + j];
    float dinv = (dn > 0.f) ? (1.0f / dn) : 0.f;
    float o = out_acc[idx] * dinv + cb + h[idx];
    o = (o > 0.f) ? o : expm1f(o);     // ELU
    o += mb;
    out_acc[idx] = o;                  // in-place prebn
    s += (double)o; sq += (double)o * (double)o;
  }
  atomicAdd(&bnacc[tid], s);
  atomicAdd(&bnacc[256 + tid], sq);
}

// ---------------------------------------------------------------------------
// K6: BN affine coefficients (biased var, eps=1e-5)
// ---------------------------------------------------------------------------
__global__ void k_bnstat(const double* __restrict__ bnacc,
                         const float* __restrict__ gamma, const float* __restrict__ beta,
                         float* __restrict__ ss)
{
  int c = threadIdx.x;
  double mu  = bnacc[c] / (double)N_ENTC;
  double var = bnacc[256 + c] / (double)N_ENTC - mu * mu;
  double istd = 1.0 / sqrt(var + 1e-5);
  float sc = (float)((double)gamma[c] * istd);
  float sh = (float)((double)beta[c] - mu * (double)sc);
  ss[c] = sc; ss[256 + c] = sh;
}

// ---------------------------------------------------------------------------
// K7: normalize + fp32 store of out_ent
// ---------------------------------------------------------------------------
__global__ __launch_bounds__(256) void k_store(
    const float* __restrict__ prebn, const float* __restrict__ ss,
    float* __restrict__ out)
{
  size_t stride = (size_t)gridDim.x * 256 * 4;
  for (size_t i = ((size_t)blockIdx.x * 256 + threadIdx.x) * 4;
       i < (size_t)N_ENTC * 256; i += stride) {
    float4 a = *(const float4*)(prebn + i);
    int c = (int)(i & 255);
    float4 o;
    o.x = a.x * ss[c + 0] + ss[256 + c + 0];
    o.y = a.y * ss[c + 1] + ss[256 + c + 1];
    o.z = a.z * ss[c + 2] + ss[256 + c + 2];
    o.w = a.w * ss[c + 3] + ss[256 + c + 3];
    *(float4*)(out + i) = o;
  }
}

// ---------------------------------------------------------------------------
// Workspace layout (peak 240,568,192 B):
//   h        [0, 133,120,000)                        fp32, alive whole pass
//   Dn       [133,120,000, 133,920,000)              zeroed by memset #1
//   bnacc    [133,920,000, 133,924,096)              zeroed by memset #1
//   s_node   [133,924,096, 134,964,096)
//   alph     [134,964,096, 138,164,096)
//   ss       [138,164,096, 138,166,144)
//   s_edge   [138,166,144, 138,168,192)
//   BIG      [138,168,192, 240,568,192)              inst (first 30.72MB, dead
//            after k_proj) then re-used as out_acc (zeroed by memset #2)
// ---------------------------------------------------------------------------
extern "C" void kernel_launch(void* const* d_in, const int* in_sizes, int n_in,
                              void* d_out, int out_size, void* d_ws, size_t ws_size,
                              hipStream_t stream)
{
  (void)in_sizes; (void)n_in; (void)out_size; (void)ws_size;

  const float* x         = (const float*)d_in[0];
  const int*   edge_idx  = (const int*)d_in[1];
  // d_in[2] = edge_order (unused)
  const int*   etype     = (const int*)d_in[3];
  const float* rel_embed = (const float*)d_in[4];
  const int*   ids       = (const int*)d_in[5];
  const float* W_in      = (const float*)d_in[6];
  const float* b_in      = (const float*)d_in[7];
  const float* W_edge    = (const float*)d_in[8];
  const float* b_edge    = (const float*)d_in[9];
  const float* W_sheaf   = (const float*)d_in[10];
  const float* b_sheaf   = (const float*)d_in[11];
  const float* W_conv    = (const float*)d_in[12];
  const float* b_conv    = (const float*)d_in[13];
  const float* conv_bias = (const float*)d_in[14];
  const float* w_rel     = (const float*)d_in[15];
  const float* loop_rel  = (const float*)d_in[16];
  const float* mod_bias  = (const float*)d_in[17];
  const float* bn_gamma  = (const float*)d_in[18];
  const float* bn_beta   = (const float*)d_in[19];

  const int* ei0 = edge_idx;            // target entities
  const int* ei1 = edge_idx + N_EDGEC;  // source instance rows

  char* ws = (char*)d_ws;
  const size_t OFF_H     = 0;                                   // 133,120,000
  const size_t OFF_DN    = OFF_H     + (size_t)NTOTC*256*4;     //     800,000
  const size_t OFF_BN    = OFF_DN    + (size_t)N_ENTC*2*4;      //       4,096
  const size_t OFF_SNODE = OFF_BN    + 4096;                    //   1,040,000
  const size_t OFF_ALPH  = OFF_SNODE + (size_t)NTOTC*2*4;       //   3,200,000
  const size_t OFF_SS    = OFF_ALPH  + (size_t)N_EDGEC*4*4;     //       2,048
  const size_t OFF_SEDGE = OFF_SS    + 2048;                    //       2,048
  const size_t OFF_BIG   = OFF_SEDGE + 2048;                    // 102,400,000

  float*  h       = (float*)(ws + OFF_H);
  float*  Dn      = (float*)(ws + OFF_DN);
  double* bnacc   = (double*)(ws + OFF_BN);
  float*  s_node  = (float*)(ws + OFF_SNODE);
  float*  alph    = (float*)(ws + OFF_ALPH);
  float*  ss      = (float*)(ws + OFF_SS);
  float*  s_edge  = (float*)(ws + OFF_SEDGE);
  float*  inst    = (float*)(ws + OFF_BIG);   // dead after k_proj
  float*  out_acc = (float*)(ws + OFF_BIG);   // zeroed after k_proj

  float* out_ent = (float*)d_out;
  float* out_rel = (float*)d_out + (size_t)N_ENTC * 256;

  // memset #1: Dn + bnacc (contiguous)
  hipMemsetAsync(ws + OFF_DN, 0, (size_t)N_ENTC*2*4 + 4096, stream);

  k_rel<<<201, 256, 0, stream>>>(rel_embed, loop_rel, W_edge, b_edge,
                                 W_sheaf, b_sheaf, w_rel, s_edge, out_rel);
  k_inst<<<N_ROWC, 256, 0, stream>>>(x, ids, inst);
  k_proj<<<(NTOTC + TM - 1) / TM, 256, 0, stream>>>(x, inst, W_in, b_in,
                                                    W_conv, b_conv, W_sheaf,
                                                    h, s_node);
  // memset #2: out_acc (re-uses the inst region, which is now dead)
  hipMemsetAsync(ws + OFF_BIG, 0, (size_t)N_ENTC*256*4, stream);

  k_alpha<<<(N_EDGEC + 255) / 256, 256, 0, stream>>>(ei0, ei1, etype,
                                                     s_node, s_edge, alph, Dn);
  k_scatter<<<(N_EDGEC + 3) / 4, 256, 0, stream>>>(ei0, ei1, alph, h, out_acc);
  k_final<<<(N_ENTC + 127) / 128, 256, 0, stream>>>(h, Dn, conv_bias, mod_bias,
                                                    out_acc, bnacc);
  k_bnstat<<<1, 256, 0, stream>>>(bnacc, bn_gamma, bn_beta, ss);
  k_store<<<8192, 256, 0, stream>>>(out_acc, ss, out_ent);
}